// Round 9
// baseline (171.023 us; speedup 1.0000x reference)
//
#include <hip/hip_runtime.h>
#include <hip/hip_bf16.h>

typedef __hip_bfloat16 bf16;

#define N_NODES 16384
#define D_IN    128
#define HID     64
#define HEADS   4
#define F1      256   // HEADS*HID
#define SEQ     128
#define SLOTS   64    // fixed CSR capacity per node (P(deg>64) ~ 1e-12 for this graph)

__device__ __forceinline__ float wave_sum(float v) {
    #pragma unroll
    for (int o = 32; o > 0; o >>= 1) v += __shfl_xor(v, o, 64);
    return v;
}
__device__ __forceinline__ float lrelu(float v) { return v > 0.f ? v : 0.2f * v; }
__device__ __forceinline__ float rdlane(float v, int l) {
    return __uint_as_float(__builtin_amdgcn_readlane(__float_as_uint(v), l));
}

#define UNPACK8(u, te, acc)                                          \
    do {                                                             \
        acc[0] += (te) * __uint_as_float((u).x << 16);               \
        acc[1] += (te) * __uint_as_float((u).x & 0xffff0000u);       \
        acc[2] += (te) * __uint_as_float((u).y << 16);               \
        acc[3] += (te) * __uint_as_float((u).y & 0xffff0000u);       \
        acc[4] += (te) * __uint_as_float((u).z << 16);               \
        acc[5] += (te) * __uint_as_float((u).z & 0xffff0000u);       \
        acc[6] += (te) * __uint_as_float((u).w << 16);               \
        acc[7] += (te) * __uint_as_float((u).w & 0xffff0000u);       \
    } while (0)

// ---------------- D1: scatter + gemm1 (+PE, +logits) fused (R21) ----------------
// R21: 8 rows/wave (was 4) -> wave count 4096->2048 -> W1 L2 streaming 512->256 MB
// (each wave streams the full 128 KB W1 regardless of row count; fewer waves = less
// traffic). This kernel is throughput-bound at ~2 blocks/CU, NOT TLP-bound: the
// R11/R13 register law does not apply here; VGPR ~70 is fine.
__global__ __launch_bounds__(256) void k_gemm1s(const float* __restrict__ x,
                                                const float* __restrict__ pe,
                                                const float* __restrict__ W1,
                                                const float* __restrict__ a_src1,
                                                const float* __restrict__ a_dst1,
                                                bf16* __restrict__ h,
                                                float* __restrict__ as1,
                                                float* __restrict__ ad1,
                                                const int* __restrict__ ei, int E, int Etot,
                                                int* __restrict__ cnt,
                                                int* __restrict__ esrc) {
    int tid = threadIdx.x, lane = tid & 63, wv = tid >> 6;

    // ---- phase 0: edge scatter (issues early; latency hidden under gemm) ----
    {
        int gtid = blockIdx.x * 256 + tid;           // 131072 threads total
        for (int e = gtid; e < Etot; e += 131072) {
            int s, d;
            if (e < E) { s = ei[e]; d = ei[E + e]; }
            else       { s = e - E; d = s; }
            int pos = atomicAdd(&cnt[d], 1);
            if (pos < SLOTS) esrc[d * SLOTS + pos] = s;
        }
    }

    // ---- gemm phase: 8 rows/wave ----
    int base = blockIdx.x * 32;
    int j4 = lane * 4;
    float2 xr[8];
    #pragma unroll
    for (int i = 0; i < 8; i++) {
        int row = base + wv * 8 + i;
        float2 xa  = *(const float2*)(x  + (size_t)row * 128 + 2 * lane);
        float2 pea = *(const float2*)(pe + (size_t)(row & (SEQ - 1)) * 128 + 2 * lane);
        xr[i].x = xa.x * 11.313708499f + pea.x;
        xr[i].y = xa.y * 11.313708499f + pea.y;
    }
    float acc[8][4] = {};
    const float4* Wv = (const float4*)W1;   // Wv[k*64 + lane] == W1[k*256 + lane*4]
    #pragma unroll 2
    for (int k2 = 0; k2 < 64; k2++) {
        float4 w0 = Wv[(size_t)(2 * k2) * 64 + lane];
        float4 w1 = Wv[(size_t)(2 * k2 + 1) * 64 + lane];
        #pragma unroll
        for (int i = 0; i < 8; i++) {
            float a0 = rdlane(xr[i].x, k2);
            float a1 = rdlane(xr[i].y, k2);
            acc[i][0] += a0 * w0.x + a1 * w1.x;
            acc[i][1] += a0 * w0.y + a1 * w1.y;
            acc[i][2] += a0 * w0.z + a1 * w1.z;
            acc[i][3] += a0 * w0.w + a1 * w1.w;
        }
    }
    float4 asv = *(const float4*)(a_src1 + j4);
    float4 adv = *(const float4*)(a_dst1 + j4);
    #pragma unroll
    for (int i = 0; i < 8; i++) {
        int row = base + wv * 8 + i;
        union { bf16 b[4]; ushort4 u; } cv;
        cv.b[0] = __float2bfloat16(acc[i][0]);
        cv.b[1] = __float2bfloat16(acc[i][1]);
        cv.b[2] = __float2bfloat16(acc[i][2]);
        cv.b[3] = __float2bfloat16(acc[i][3]);
        *(ushort4*)(h + (size_t)row * 256 + j4) = cv.u;
        float vs = acc[i][0] * asv.x + acc[i][1] * asv.y + acc[i][2] * asv.z + acc[i][3] * asv.w;
        float vd = acc[i][0] * adv.x + acc[i][1] * adv.y + acc[i][2] * adv.z + acc[i][3] * adv.w;
        #pragma unroll
        for (int o = 1; o < 16; o <<= 1) {
            vs += __shfl_xor(vs, o);
            vd += __shfl_xor(vd, o);
        }
        if ((lane & 15) == 0) {
            as1[row * 4 + (lane >> 4)] = vs;
            ad1[row * 4 + (lane >> 4)] = vd;
        }
    }
}

// ---------------- D2: fused softmax + agg1 + gemm2 (R21: 4 nodes/block) ----------------
// R21: 4096 blocks x 4 nodes (was 2048 x 8). Same per-node structure (R19 known-good);
// finer block granularity fixes the drain-tail that capped OccupancyPercent at 44%
// with exactly-8-blocks/CU. LDS 9.2 KB.
// NOTE (kernel law, R11/R13): TLP-bound — VGPR must stay < 64, keep lean.
__global__ __launch_bounds__(256) void k_agg1_gemm2(
        const int* __restrict__ cnt, const int* __restrict__ esrc,
        const float* __restrict__ as1, const float* __restrict__ ad1,
        const bf16* __restrict__ h,
        const float* __restrict__ b1,
        const float* __restrict__ W2,
        const float* __restrict__ a_src2, const float* __restrict__ a_dst2,
        bf16* __restrict__ h2, float* __restrict__ as2, float* __restrict__ ad2) {
    __shared__ float hs[4][256];
    __shared__ float scr[1024];   // phase A/B: ts[(it*4+wv)*64+lane]; gemm2: part[(wv*4+r)*64+lane]
    __shared__ int   ss[4][64];   // masked edge indices, shared by all 4 waves
    int tid = threadIdx.x, lane = tid & 63, wv = tid >> 6;
    int dbase = blockIdx.x * 4;
    int eg = lane >> 3;   // octet index (owns slots 4eg..4eg+3 per window)
    int cg_ = lane & 7;   // channel group (8 channels, 16 B)
    const bf16* hbase = h + (size_t)wv * 64 + cg_ * 8;

    int cv4 = cnt[dbase + (lane & 3)];               // 4 degrees, one load

    // ---- phase A: normalized per-head edge weights + staged indices ----
    #pragma unroll 4
    for (int it = 0; it < 4; it++) {
        int d = dbase + it;
        int deg = min(__shfl(cv4, it), SLOTS);
        int s = esrc[(size_t)d * SLOTS + lane] & (N_NODES - 1);   // tail -> masked idx
        float av = as1[(size_t)s * 4 + wv];
        float adw = ad1[d * 4 + wv];
        float t = (lane < deg) ? __expf(lrelu(av + adw) - 40.f) : 0.f;
        float inv = 1.f / wave_sum(t);                // den > 0 (self-loop)
        scr[(it * 4 + wv) * 64 + lane] = t * inv;
        ss[it][lane] = s;                             // same value from all 4 waves
    }
    // no barrier: each wave reads only ts/ss values it wrote itself

    // ---- phase B: contiguous-4 octet gather; indices + weights from LDS ----
    #pragma unroll 2
    for (int it = 0; it < 4; it++) {
        int deg = min(__shfl(cv4, it), SLOTS);
        const float* tsr = &scr[(it * 4 + wv) * 64];

        float acc[8] = {0, 0, 0, 0, 0, 0, 0, 0};
        if (4 * eg < deg) {                            // window 0 (slots 0..31)
            int4   sv = *(const int4*)&ss[it][4 * eg];         // ds_read_b128 broadcast
            float4 tv = *(const float4*)(tsr + 4 * eg);
            uint4 u0 = *(const uint4*)(hbase + (size_t)sv.x * 256);
            uint4 u1 = *(const uint4*)(hbase + (size_t)sv.y * 256);
            uint4 u2 = *(const uint4*)(hbase + (size_t)sv.z * 256);
            uint4 u3 = *(const uint4*)(hbase + (size_t)sv.w * 256);
            UNPACK8(u0, tv.x, acc);
            UNPACK8(u1, tv.y, acc);
            UNPACK8(u2, tv.z, acc);
            UNPACK8(u3, tv.w, acc);
        }
        for (int sub = 32; sub < deg; sub += 32) {     // rare: deg > 32
            if (sub + 4 * eg < deg) {
                int4   s2 = *(const int4*)&ss[it][sub + 4 * eg];
                float4 t2 = *(const float4*)(tsr + sub + 4 * eg);
                uint4 u0 = *(const uint4*)(hbase + (size_t)s2.x * 256);
                uint4 u1 = *(const uint4*)(hbase + (size_t)s2.y * 256);
                uint4 u2 = *(const uint4*)(hbase + (size_t)s2.z * 256);
                uint4 u3 = *(const uint4*)(hbase + (size_t)s2.w * 256);
                UNPACK8(u0, t2.x, acc);
                UNPACK8(u1, t2.y, acc);
                UNPACK8(u2, t2.z, acc);
                UNPACK8(u3, t2.w, acc);
            }
        }
        #pragma unroll
        for (int j = 0; j < 8; j++) {
            acc[j] += __shfl_xor(acc[j], 8);
            acc[j] += __shfl_xor(acc[j], 16);
            acc[j] += __shfl_xor(acc[j], 32);
        }
        if (lane < 8) {
            int cbase = wv * 64 + lane * 8;
            const float4* b1v = (const float4*)(b1 + cbase);   // L1-hot after first iter
            float4 bb0 = b1v[0], bb1 = b1v[1];
            float o[8];
            o[0] = acc[0] + bb0.x; o[1] = acc[1] + bb0.y;
            o[2] = acc[2] + bb0.z; o[3] = acc[3] + bb0.w;
            o[4] = acc[4] + bb1.x; o[5] = acc[5] + bb1.y;
            o[6] = acc[6] + bb1.z; o[7] = acc[7] + bb1.w;
            #pragma unroll
            for (int j = 0; j < 8; j++)
                o[j] = o[j] > 0.f ? o[j] : (__expf(o[j]) - 1.f);   // elu
            float4* dst = (float4*)&hs[it][cbase];
            dst[0] = make_float4(o[0], o[1], o[2], o[3]);
            dst[1] = make_float4(o[4], o[5], o[6], o[7]);
        }
    }
    __syncthreads();   // hs complete; ts (scr) dead from here -> reuse as part

    // ---- gemm2 on the 4 rows in LDS, K-split across the 4 waves ----
    {
        float acc2[4] = {0, 0, 0, 0};
        const int k4base = wv * 16;
        for (int kk = 0; kk < 16; kk++) {
            int k4 = k4base + kk;
            const float* wp = W2 + (size_t)k4 * 256 + lane;   // W2[(k4*4+q)*64 + lane]
            float w0 = wp[0], w1 = wp[64], w2 = wp[128], w3 = wp[192];
            #pragma unroll
            for (int r = 0; r < 4; r++) {
                float4 u = *(const float4*)&hs[r][k4 * 4];    // wave-uniform -> broadcast
                acc2[r] += u.x * w0 + u.y * w1 + u.z * w2 + u.w * w3;
            }
        }
        #pragma unroll
        for (int r = 0; r < 4; r++) scr[(wv * 4 + r) * 64 + lane] = acc2[r];
    }
    __syncthreads();
    {
        int r = wv;                                   // one row per wave
        float a0 = scr[(0 * 4 + r) * 64 + lane] + scr[(1 * 4 + r) * 64 + lane]
                 + scr[(2 * 4 + r) * 64 + lane] + scr[(3 * 4 + r) * 64 + lane];
        float asj = a_src2[lane], adj = a_dst2[lane];
        int n0 = dbase + r;
        h2[(size_t)n0 * 64 + lane] = __float2bfloat16(a0);
        float va0 = wave_sum(a0 * asj);
        float vd0 = wave_sum(a0 * adj);
        if (lane == 0) {
            as2[n0] = va0; ad2[n0] = vd0;
        }
    }
}

// ---------------- D3: fused softmax + agg2 -> out (R18 known-good) ----------------
__global__ __launch_bounds__(256) void k_agg2(const int* __restrict__ cnt,
                                              const int* __restrict__ esrc,
                                              const float* __restrict__ as2,
                                              const float* __restrict__ ad2,
                                              const bf16* __restrict__ h2,
                                              const float* __restrict__ b2v,
                                              float* __restrict__ out) {
    __shared__ float ts[4][64];
    int tid = threadIdx.x, lane = tid & 63, wv = tid >> 6;
    int d = blockIdx.x * 4 + wv;
    int deg = min(cnt[d], SLOTS);
    int eg = lane >> 3, cg_ = lane & 7;
    const bf16* hbase = h2 + cg_ * 8;
    const int4* ep4 = (const int4*)(esrc + (size_t)d * SLOTS);

    // issue gather-index load first (independent of the t chain)
    int4 sv = ep4[eg];
    sv.x &= N_NODES - 1; sv.y &= N_NODES - 1;
    sv.z &= N_NODES - 1; sv.w &= N_NODES - 1;

    // t chain (runs concurrently with the h2 gathers below in HW)
    int s = esrc[(size_t)d * SLOTS + lane] & (N_NODES - 1);
    float av = as2[s];
    float adw = ad2[d];
    float t = (lane < deg) ? __expf(lrelu(av + adw) - 40.f) : 0.f;
    float inv = 1.f / wave_sum(t);
    ts[wv][lane] = t * inv;

    float acc[8] = {0, 0, 0, 0, 0, 0, 0, 0};
    if (4 * eg < deg) {                                // window 0 (slots 0..31)
        uint4 u0 = *(const uint4*)(hbase + (size_t)sv.x * 64);
        uint4 u1 = *(const uint4*)(hbase + (size_t)sv.y * 64);
        uint4 u2 = *(const uint4*)(hbase + (size_t)sv.z * 64);
        uint4 u3 = *(const uint4*)(hbase + (size_t)sv.w * 64);
        float4 tv = *(const float4*)&ts[wv][4 * eg];
        UNPACK8(u0, tv.x, acc);
        UNPACK8(u1, tv.y, acc);
        UNPACK8(u2, tv.z, acc);
        UNPACK8(u3, tv.w, acc);
    }
    for (int sub = 32; sub < deg; sub += 32) {         // rare: deg > 32
        int4 s2 = ep4[(sub >> 2) + eg];
        s2.x &= N_NODES - 1; s2.y &= N_NODES - 1;
        s2.z &= N_NODES - 1; s2.w &= N_NODES - 1;
        if (sub + 4 * eg < deg) {
            uint4 u0 = *(const uint4*)(hbase + (size_t)s2.x * 64);
            uint4 u1 = *(const uint4*)(hbase + (size_t)s2.y * 64);
            uint4 u2 = *(const uint4*)(hbase + (size_t)s2.z * 64);
            uint4 u3 = *(const uint4*)(hbase + (size_t)s2.w * 64);
            float4 t2 = *(const float4*)&ts[wv][sub + 4 * eg];
            UNPACK8(u0, t2.x, acc);
            UNPACK8(u1, t2.y, acc);
            UNPACK8(u2, t2.z, acc);
            UNPACK8(u3, t2.w, acc);
        }
    }
    #pragma unroll
    for (int j = 0; j < 8; j++) {
        acc[j] += __shfl_xor(acc[j], 8);
        acc[j] += __shfl_xor(acc[j], 16);
        acc[j] += __shfl_xor(acc[j], 32);
    }
    if (lane < 8) {
        int cbase = lane * 8;
        float o[8];
        #pragma unroll
        for (int j = 0; j < 8; j++) o[j] = acc[j] + b2v[cbase + j];
        float4* dst = (float4*)(out + (size_t)d * 64 + cbase);
        dst[0] = make_float4(o[0], o[1], o[2], o[3]);
        dst[1] = make_float4(o[4], o[5], o[6], o[7]);
    }
}

extern "C" void kernel_launch(void* const* d_in, const int* in_sizes, int n_in,
                              void* d_out, int out_size, void* d_ws, size_t ws_size,
                              hipStream_t stream) {
    const float* x    = (const float*)d_in[0];
    const int*   ei   = (const int*)  d_in[1];
    const float* pe   = (const float*)d_in[2];
    const float* W1   = (const float*)d_in[3];
    const float* a_s1 = (const float*)d_in[4];
    const float* a_d1 = (const float*)d_in[5];
    const float* b1   = (const float*)d_in[6];
    const float* W2   = (const float*)d_in[7];
    const float* a_s2 = (const float*)d_in[8];
    const float* a_d2 = (const float*)d_in[9];
    const float* b2   = (const float*)d_in[10];

    const int E    = in_sizes[1] / 2;
    const int n    = N_NODES;
    const int Etot = E + n;

    // workspace carve-up (256B aligned) — footprint ~14.6 MB
    char* p = (char*)d_ws;
    auto alloc = [&](size_t bytes) -> void* {
        void* r = (void*)p;
        p += (bytes + 255) & ~(size_t)255;
        return r;
    };
    int*   cnt     = (int*)  alloc((size_t)n * 4);
    int*   esrc    = (int*)  alloc((size_t)n * SLOTS * 4);
    bf16*  h       = (bf16*) alloc((size_t)n * F1 * 2);
    float* as1     = (float*)alloc((size_t)n * HEADS * 4);
    float* ad1     = (float*)alloc((size_t)n * HEADS * 4);
    bf16*  h2      = (bf16*) alloc((size_t)n * HID * 2);
    float* as2     = (float*)alloc((size_t)n * 4);
    float* ad2     = (float*)alloc((size_t)n * 4);

    hipMemsetAsync(cnt, 0, (size_t)n * 4, stream);   // cnt zeroing

    k_gemm1s    <<<n / 32, 256, 0, stream>>>(x, pe, W1, a_s1, a_d1, h, as1, ad1,
                                             ei, E, Etot, cnt, esrc);
    k_agg1_gemm2<<<n / 4, 256, 0, stream>>>(cnt, esrc, as1, ad1, h, b1,
                                            W2, a_s2, a_d2, h2, as2, ad2);
    k_agg2      <<<n / 4, 256, 0, stream>>>(cnt, esrc, as2, ad2, h2, b2, (float*)d_out);
}

// Round 10
// 170.789 us; speedup vs baseline: 1.0014x; 1.0014x over previous
//
#include <hip/hip_runtime.h>
#include <hip/hip_bf16.h>

typedef __hip_bfloat16 bf16;

#define N_NODES 16384
#define D_IN    128
#define HID     64
#define HEADS   4
#define F1      256   // HEADS*HID
#define SEQ     128
#define SLOTS   64    // fixed CSR capacity per node (P(deg>64) ~ 1e-12 for this graph)

__device__ __forceinline__ float wave_sum(float v) {
    #pragma unroll
    for (int o = 32; o > 0; o >>= 1) v += __shfl_xor(v, o, 64);
    return v;
}
__device__ __forceinline__ float lrelu(float v) { return v > 0.f ? v : 0.2f * v; }
__device__ __forceinline__ float rdlane(float v, int l) {
    return __uint_as_float(__builtin_amdgcn_readlane(__float_as_uint(v), l));
}

#define UNPACK8(u, te, acc)                                          \
    do {                                                             \
        acc[0] += (te) * __uint_as_float((u).x << 16);               \
        acc[1] += (te) * __uint_as_float((u).x & 0xffff0000u);       \
        acc[2] += (te) * __uint_as_float((u).y << 16);               \
        acc[3] += (te) * __uint_as_float((u).y & 0xffff0000u);       \
        acc[4] += (te) * __uint_as_float((u).z << 16);               \
        acc[5] += (te) * __uint_as_float((u).z & 0xffff0000u);       \
        acc[6] += (te) * __uint_as_float((u).w << 16);               \
        acc[7] += (te) * __uint_as_float((u).w & 0xffff0000u);       \
    } while (0)

// ---------------- D1: scatter + gemm1 (+PE, +logits) fused (R22) ----------------
// R22: W1 staged through LDS per block (4 chunks x 32 K-rows x 256 cols = 32 KB),
// shared by all 4 waves. Replaces per-wave L2 streaming of the full 128 KB W1
// (R9 counters: VALUBusy 31%, Occ 20% -> L2-load latency-bound, NOT bandwidth:
// FETCH was only 5.8 MB). ds_read_b128 ~12cy pipelined vs L2 ~200cy. Back to
// 4 rows/wave, grid 1024 (R21's 8-row/512-block variant regressed: 2 blk/CU).
__global__ __launch_bounds__(256) void k_gemm1s(const float* __restrict__ x,
                                                const float* __restrict__ pe,
                                                const float* __restrict__ W1,
                                                const float* __restrict__ a_src1,
                                                const float* __restrict__ a_dst1,
                                                bf16* __restrict__ h,
                                                float* __restrict__ as1,
                                                float* __restrict__ ad1,
                                                const int* __restrict__ ei, int E, int Etot,
                                                int* __restrict__ cnt,
                                                int* __restrict__ esrc) {
    __shared__ float4 ws[2048];   // 32 K-rows x 64 float4 = 32 KB
    int tid = threadIdx.x, lane = tid & 63, wv = tid >> 6;

    // ---- phase 0: edge scatter (issues early; latency hidden under gemm) ----
    {
        int gtid = blockIdx.x * 256 + tid;           // 262144 threads total
        for (int e = gtid; e < Etot; e += 262144) {
            int s, d;
            if (e < E) { s = ei[e]; d = ei[E + e]; }
            else       { s = e - E; d = s; }
            int pos = atomicAdd(&cnt[d], 1);
            if (pos < SLOTS) esrc[d * SLOTS + pos] = s;
        }
    }

    // ---- gemm phase: 4 rows/wave, W1 via LDS chunks ----
    int base = blockIdx.x * 16;
    int j4 = lane * 4;
    float2 xr[4];
    #pragma unroll
    for (int i = 0; i < 4; i++) {
        int row = base + wv * 4 + i;
        float2 xa  = *(const float2*)(x  + (size_t)row * 128 + 2 * lane);
        float2 pea = *(const float2*)(pe + (size_t)(row & (SEQ - 1)) * 128 + 2 * lane);
        xr[i].x = xa.x * 11.313708499f + pea.x;
        xr[i].y = xa.y * 11.313708499f + pea.y;
    }
    float acc[4][4] = {};
    const float4* Wv = (const float4*)W1;   // Wv[k*64 + j] == W1[k*256 + j*4]
    for (int c = 0; c < 4; c++) {           // 4 chunks of 32 K-rows
        if (c > 0) __syncthreads();         // previous chunk fully consumed
        const float4* src = Wv + (size_t)c * 2048;
        #pragma unroll
        for (int i = 0; i < 8; i++) ws[i * 256 + tid] = src[i * 256 + tid];
        __syncthreads();
        #pragma unroll 4
        for (int lk2 = 0; lk2 < 16; lk2++) {
            int k2 = c * 16 + lk2;          // global float2-index (rdlane source)
            float4 w0 = ws[(2 * lk2) * 64 + lane];
            float4 w1 = ws[(2 * lk2 + 1) * 64 + lane];
            #pragma unroll
            for (int i = 0; i < 4; i++) {
                float a0 = rdlane(xr[i].x, k2);
                float a1 = rdlane(xr[i].y, k2);
                acc[i][0] += a0 * w0.x + a1 * w1.x;
                acc[i][1] += a0 * w0.y + a1 * w1.y;
                acc[i][2] += a0 * w0.z + a1 * w1.z;
                acc[i][3] += a0 * w0.w + a1 * w1.w;
            }
        }
    }
    float4 asv = *(const float4*)(a_src1 + j4);
    float4 adv = *(const float4*)(a_dst1 + j4);
    #pragma unroll
    for (int i = 0; i < 4; i++) {
        int row = base + wv * 4 + i;
        union { bf16 b[4]; ushort4 u; } cv;
        cv.b[0] = __float2bfloat16(acc[i][0]);
        cv.b[1] = __float2bfloat16(acc[i][1]);
        cv.b[2] = __float2bfloat16(acc[i][2]);
        cv.b[3] = __float2bfloat16(acc[i][3]);
        *(ushort4*)(h + (size_t)row * 256 + j4) = cv.u;
        float vs = acc[i][0] * asv.x + acc[i][1] * asv.y + acc[i][2] * asv.z + acc[i][3] * asv.w;
        float vd = acc[i][0] * adv.x + acc[i][1] * adv.y + acc[i][2] * adv.z + acc[i][3] * adv.w;
        #pragma unroll
        for (int o = 1; o < 16; o <<= 1) {
            vs += __shfl_xor(vs, o);
            vd += __shfl_xor(vd, o);
        }
        if ((lane & 15) == 0) {
            as1[row * 4 + (lane >> 4)] = vs;
            ad1[row * 4 + (lane >> 4)] = vd;
        }
    }
}

// ---------------- D2: fused softmax + agg1 + gemm2 (R21 known-good: 4 nodes/block) ----------------
// 4096 blocks x 4 nodes; wave = head. Phase A stages normalized edge weights (scr)
// + masked indices (ss) in LDS, no barrier; phase B contiguous-4 octet gather with
// ds_read_b128 broadcasts. LDS 9.2 KB.
// NOTE (kernel law, R11/R13): TLP-bound — VGPR must stay < 64, keep lean.
__global__ __launch_bounds__(256) void k_agg1_gemm2(
        const int* __restrict__ cnt, const int* __restrict__ esrc,
        const float* __restrict__ as1, const float* __restrict__ ad1,
        const bf16* __restrict__ h,
        const float* __restrict__ b1,
        const float* __restrict__ W2,
        const float* __restrict__ a_src2, const float* __restrict__ a_dst2,
        bf16* __restrict__ h2, float* __restrict__ as2, float* __restrict__ ad2) {
    __shared__ float hs[4][256];
    __shared__ float scr[1024];   // phase A/B: ts[(it*4+wv)*64+lane]; gemm2: part[(wv*4+r)*64+lane]
    __shared__ int   ss[4][64];   // masked edge indices, shared by all 4 waves
    int tid = threadIdx.x, lane = tid & 63, wv = tid >> 6;
    int dbase = blockIdx.x * 4;
    int eg = lane >> 3;   // octet index (owns slots 4eg..4eg+3 per window)
    int cg_ = lane & 7;   // channel group (8 channels, 16 B)
    const bf16* hbase = h + (size_t)wv * 64 + cg_ * 8;

    int cv4 = cnt[dbase + (lane & 3)];               // 4 degrees, one load

    // ---- phase A: normalized per-head edge weights + staged indices ----
    #pragma unroll 4
    for (int it = 0; it < 4; it++) {
        int d = dbase + it;
        int deg = min(__shfl(cv4, it), SLOTS);
        int s = esrc[(size_t)d * SLOTS + lane] & (N_NODES - 1);   // tail -> masked idx
        float av = as1[(size_t)s * 4 + wv];
        float adw = ad1[d * 4 + wv];
        float t = (lane < deg) ? __expf(lrelu(av + adw) - 40.f) : 0.f;
        float inv = 1.f / wave_sum(t);                // den > 0 (self-loop)
        scr[(it * 4 + wv) * 64 + lane] = t * inv;
        ss[it][lane] = s;                             // same value from all 4 waves
    }
    // no barrier: each wave reads only ts/ss values it wrote itself

    // ---- phase B: contiguous-4 octet gather; indices + weights from LDS ----
    #pragma unroll 2
    for (int it = 0; it < 4; it++) {
        int deg = min(__shfl(cv4, it), SLOTS);
        const float* tsr = &scr[(it * 4 + wv) * 64];

        float acc[8] = {0, 0, 0, 0, 0, 0, 0, 0};
        if (4 * eg < deg) {                            // window 0 (slots 0..31)
            int4   sv = *(const int4*)&ss[it][4 * eg];         // ds_read_b128 broadcast
            float4 tv = *(const float4*)(tsr + 4 * eg);
            uint4 u0 = *(const uint4*)(hbase + (size_t)sv.x * 256);
            uint4 u1 = *(const uint4*)(hbase + (size_t)sv.y * 256);
            uint4 u2 = *(const uint4*)(hbase + (size_t)sv.z * 256);
            uint4 u3 = *(const uint4*)(hbase + (size_t)sv.w * 256);
            UNPACK8(u0, tv.x, acc);
            UNPACK8(u1, tv.y, acc);
            UNPACK8(u2, tv.z, acc);
            UNPACK8(u3, tv.w, acc);
        }
        for (int sub = 32; sub < deg; sub += 32) {     // rare: deg > 32
            if (sub + 4 * eg < deg) {
                int4   s2 = *(const int4*)&ss[it][sub + 4 * eg];
                float4 t2 = *(const float4*)(tsr + sub + 4 * eg);
                uint4 u0 = *(const uint4*)(hbase + (size_t)s2.x * 256);
                uint4 u1 = *(const uint4*)(hbase + (size_t)s2.y * 256);
                uint4 u2 = *(const uint4*)(hbase + (size_t)s2.z * 256);
                uint4 u3 = *(const uint4*)(hbase + (size_t)s2.w * 256);
                UNPACK8(u0, t2.x, acc);
                UNPACK8(u1, t2.y, acc);
                UNPACK8(u2, t2.z, acc);
                UNPACK8(u3, t2.w, acc);
            }
        }
        #pragma unroll
        for (int j = 0; j < 8; j++) {
            acc[j] += __shfl_xor(acc[j], 8);
            acc[j] += __shfl_xor(acc[j], 16);
            acc[j] += __shfl_xor(acc[j], 32);
        }
        if (lane < 8) {
            int cbase = wv * 64 + lane * 8;
            const float4* b1v = (const float4*)(b1 + cbase);   // L1-hot after first iter
            float4 bb0 = b1v[0], bb1 = b1v[1];
            float o[8];
            o[0] = acc[0] + bb0.x; o[1] = acc[1] + bb0.y;
            o[2] = acc[2] + bb0.z; o[3] = acc[3] + bb0.w;
            o[4] = acc[4] + bb1.x; o[5] = acc[5] + bb1.y;
            o[6] = acc[6] + bb1.z; o[7] = acc[7] + bb1.w;
            #pragma unroll
            for (int j = 0; j < 8; j++)
                o[j] = o[j] > 0.f ? o[j] : (__expf(o[j]) - 1.f);   // elu
            float4* dst = (float4*)&hs[it][cbase];
            dst[0] = make_float4(o[0], o[1], o[2], o[3]);
            dst[1] = make_float4(o[4], o[5], o[6], o[7]);
        }
    }
    __syncthreads();   // hs complete; ts (scr) dead from here -> reuse as part

    // ---- gemm2 on the 4 rows in LDS, K-split across the 4 waves ----
    {
        float acc2[4] = {0, 0, 0, 0};
        const int k4base = wv * 16;
        for (int kk = 0; kk < 16; kk++) {
            int k4 = k4base + kk;
            const float* wp = W2 + (size_t)k4 * 256 + lane;   // W2[(k4*4+q)*64 + lane]
            float w0 = wp[0], w1 = wp[64], w2 = wp[128], w3 = wp[192];
            #pragma unroll
            for (int r = 0; r < 4; r++) {
                float4 u = *(const float4*)&hs[r][k4 * 4];    // wave-uniform -> broadcast
                acc2[r] += u.x * w0 + u.y * w1 + u.z * w2 + u.w * w3;
            }
        }
        #pragma unroll
        for (int r = 0; r < 4; r++) scr[(wv * 4 + r) * 64 + lane] = acc2[r];
    }
    __syncthreads();
    {
        int r = wv;                                   // one row per wave
        float a0 = scr[(0 * 4 + r) * 64 + lane] + scr[(1 * 4 + r) * 64 + lane]
                 + scr[(2 * 4 + r) * 64 + lane] + scr[(3 * 4 + r) * 64 + lane];
        float asj = a_src2[lane], adj = a_dst2[lane];
        int n0 = dbase + r;
        h2[(size_t)n0 * 64 + lane] = __float2bfloat16(a0);
        float va0 = wave_sum(a0 * asj);
        float vd0 = wave_sum(a0 * adj);
        if (lane == 0) {
            as2[n0] = va0; ad2[n0] = vd0;
        }
    }
}

// ---------------- D3: fused softmax + agg2 -> out (R18 known-good) ----------------
__global__ __launch_bounds__(256) void k_agg2(const int* __restrict__ cnt,
                                              const int* __restrict__ esrc,
                                              const float* __restrict__ as2,
                                              const float* __restrict__ ad2,
                                              const bf16* __restrict__ h2,
                                              const float* __restrict__ b2v,
                                              float* __restrict__ out) {
    __shared__ float ts[4][64];
    int tid = threadIdx.x, lane = tid & 63, wv = tid >> 6;
    int d = blockIdx.x * 4 + wv;
    int deg = min(cnt[d], SLOTS);
    int eg = lane >> 3, cg_ = lane & 7;
    const bf16* hbase = h2 + cg_ * 8;
    const int4* ep4 = (const int4*)(esrc + (size_t)d * SLOTS);

    // issue gather-index load first (independent of the t chain)
    int4 sv = ep4[eg];
    sv.x &= N_NODES - 1; sv.y &= N_NODES - 1;
    sv.z &= N_NODES - 1; sv.w &= N_NODES - 1;

    // t chain (runs concurrently with the h2 gathers below in HW)
    int s = esrc[(size_t)d * SLOTS + lane] & (N_NODES - 1);
    float av = as2[s];
    float adw = ad2[d];
    float t = (lane < deg) ? __expf(lrelu(av + adw) - 40.f) : 0.f;
    float inv = 1.f / wave_sum(t);
    ts[wv][lane] = t * inv;

    float acc[8] = {0, 0, 0, 0, 0, 0, 0, 0};
    if (4 * eg < deg) {                                // window 0 (slots 0..31)
        uint4 u0 = *(const uint4*)(hbase + (size_t)sv.x * 64);
        uint4 u1 = *(const uint4*)(hbase + (size_t)sv.y * 64);
        uint4 u2 = *(const uint4*)(hbase + (size_t)sv.z * 64);
        uint4 u3 = *(const uint4*)(hbase + (size_t)sv.w * 64);
        float4 tv = *(const float4*)&ts[wv][4 * eg];
        UNPACK8(u0, tv.x, acc);
        UNPACK8(u1, tv.y, acc);
        UNPACK8(u2, tv.z, acc);
        UNPACK8(u3, tv.w, acc);
    }
    for (int sub = 32; sub < deg; sub += 32) {         // rare: deg > 32
        int4 s2 = ep4[(sub >> 2) + eg];
        s2.x &= N_NODES - 1; s2.y &= N_NODES - 1;
        s2.z &= N_NODES - 1; s2.w &= N_NODES - 1;
        if (sub + 4 * eg < deg) {
            uint4 u0 = *(const uint4*)(hbase + (size_t)s2.x * 64);
            uint4 u1 = *(const uint4*)(hbase + (size_t)s2.y * 64);
            uint4 u2 = *(const uint4*)(hbase + (size_t)s2.z * 64);
            uint4 u3 = *(const uint4*)(hbase + (size_t)s2.w * 64);
            float4 t2 = *(const float4*)&ts[wv][sub + 4 * eg];
            UNPACK8(u0, t2.x, acc);
            UNPACK8(u1, t2.y, acc);
            UNPACK8(u2, t2.z, acc);
            UNPACK8(u3, t2.w, acc);
        }
    }
    #pragma unroll
    for (int j = 0; j < 8; j++) {
        acc[j] += __shfl_xor(acc[j], 8);
        acc[j] += __shfl_xor(acc[j], 16);
        acc[j] += __shfl_xor(acc[j], 32);
    }
    if (lane < 8) {
        int cbase = lane * 8;
        float o[8];
        #pragma unroll
        for (int j = 0; j < 8; j++) o[j] = acc[j] + b2v[cbase + j];
        float4* dst = (float4*)(out + (size_t)d * 64 + cbase);
        dst[0] = make_float4(o[0], o[1], o[2], o[3]);
        dst[1] = make_float4(o[4], o[5], o[6], o[7]);
    }
}

extern "C" void kernel_launch(void* const* d_in, const int* in_sizes, int n_in,
                              void* d_out, int out_size, void* d_ws, size_t ws_size,
                              hipStream_t stream) {
    const float* x    = (const float*)d_in[0];
    const int*   ei   = (const int*)  d_in[1];
    const float* pe   = (const float*)d_in[2];
    const float* W1   = (const float*)d_in[3];
    const float* a_s1 = (const float*)d_in[4];
    const float* a_d1 = (const float*)d_in[5];
    const float* b1   = (const float*)d_in[6];
    const float* W2   = (const float*)d_in[7];
    const float* a_s2 = (const float*)d_in[8];
    const float* a_d2 = (const float*)d_in[9];
    const float* b2   = (const float*)d_in[10];

    const int E    = in_sizes[1] / 2;
    const int n    = N_NODES;
    const int Etot = E + n;

    // workspace carve-up (256B aligned) — footprint ~14.6 MB
    char* p = (char*)d_ws;
    auto alloc = [&](size_t bytes) -> void* {
        void* r = (void*)p;
        p += (bytes + 255) & ~(size_t)255;
        return r;
    };
    int*   cnt     = (int*)  alloc((size_t)n * 4);
    int*   esrc    = (int*)  alloc((size_t)n * SLOTS * 4);
    bf16*  h       = (bf16*) alloc((size_t)n * F1 * 2);
    float* as1     = (float*)alloc((size_t)n * HEADS * 4);
    float* ad1     = (float*)alloc((size_t)n * HEADS * 4);
    bf16*  h2      = (bf16*) alloc((size_t)n * HID * 2);
    float* as2     = (float*)alloc((size_t)n * 4);
    float* ad2     = (float*)alloc((size_t)n * 4);

    hipMemsetAsync(cnt, 0, (size_t)n * 4, stream);   // cnt zeroing

    k_gemm1s    <<<n / 16, 256, 0, stream>>>(x, pe, W1, a_s1, a_d1, h, as1, ad1,
                                             ei, E, Etot, cnt, esrc);
    k_agg1_gemm2<<<n / 4, 256, 0, stream>>>(cnt, esrc, as1, ad1, h, b1,
                                            W2, a_s2, a_d2, h2, as2, ad2);
    k_agg2      <<<n / 4, 256, 0, stream>>>(cnt, esrc, as2, ad2, h2, b2, (float*)d_out);
}

// Round 11
// 166.939 us; speedup vs baseline: 1.0245x; 1.0231x over previous
//
#include <hip/hip_runtime.h>
#include <hip/hip_bf16.h>

typedef __hip_bfloat16 bf16;

#define N_NODES 16384
#define D_IN    128
#define HID     64
#define HEADS   4
#define F1      256   // HEADS*HID
#define SEQ     128
#define SLOTS   64    // fixed CSR capacity per node (P(deg>64) ~ 1e-12 for this graph)

__device__ __forceinline__ float wave_sum(float v) {
    #pragma unroll
    for (int o = 32; o > 0; o >>= 1) v += __shfl_xor(v, o, 64);
    return v;
}
__device__ __forceinline__ float lrelu(float v) { return v > 0.f ? v : 0.2f * v; }
__device__ __forceinline__ float rdlane(float v, int l) {
    return __uint_as_float(__builtin_amdgcn_readlane(__float_as_uint(v), l));
}
__device__ __forceinline__ float bfu(unsigned short u) {
    return __uint_as_float((unsigned)u << 16);
}

// ---------------- D1: scatter + gemm1 (+PE, +logits) fused (R22 known-good) ----------------
// W1 staged through LDS per block (4 chunks x 32 K-rows = 32 KB), 4 rows/wave, grid 1024.
__global__ __launch_bounds__(256) void k_gemm1s(const float* __restrict__ x,
                                                const float* __restrict__ pe,
                                                const float* __restrict__ W1,
                                                const float* __restrict__ a_src1,
                                                const float* __restrict__ a_dst1,
                                                bf16* __restrict__ h,
                                                float* __restrict__ as1,
                                                float* __restrict__ ad1,
                                                const int* __restrict__ ei, int E, int Etot,
                                                int* __restrict__ cnt,
                                                int* __restrict__ esrc) {
    __shared__ float4 ws[2048];   // 32 K-rows x 64 float4 = 32 KB
    int tid = threadIdx.x, lane = tid & 63, wv = tid >> 6;

    // ---- phase 0: edge scatter (issues early; latency hidden under gemm) ----
    {
        int gtid = blockIdx.x * 256 + tid;           // 262144 threads total
        for (int e = gtid; e < Etot; e += 262144) {
            int s, d;
            if (e < E) { s = ei[e]; d = ei[E + e]; }
            else       { s = e - E; d = s; }
            int pos = atomicAdd(&cnt[d], 1);
            if (pos < SLOTS) esrc[d * SLOTS + pos] = s;
        }
    }

    // ---- gemm phase: 4 rows/wave, W1 via LDS chunks ----
    int base = blockIdx.x * 16;
    int j4 = lane * 4;
    float2 xr[4];
    #pragma unroll
    for (int i = 0; i < 4; i++) {
        int row = base + wv * 4 + i;
        float2 xa  = *(const float2*)(x  + (size_t)row * 128 + 2 * lane);
        float2 pea = *(const float2*)(pe + (size_t)(row & (SEQ - 1)) * 128 + 2 * lane);
        xr[i].x = xa.x * 11.313708499f + pea.x;
        xr[i].y = xa.y * 11.313708499f + pea.y;
    }
    float acc[4][4] = {};
    const float4* Wv = (const float4*)W1;   // Wv[k*64 + j] == W1[k*256 + j*4]
    for (int c = 0; c < 4; c++) {           // 4 chunks of 32 K-rows
        if (c > 0) __syncthreads();         // previous chunk fully consumed
        const float4* src = Wv + (size_t)c * 2048;
        #pragma unroll
        for (int i = 0; i < 8; i++) ws[i * 256 + tid] = src[i * 256 + tid];
        __syncthreads();
        #pragma unroll 4
        for (int lk2 = 0; lk2 < 16; lk2++) {
            int k2 = c * 16 + lk2;          // global float2-index (rdlane source)
            float4 w0 = ws[(2 * lk2) * 64 + lane];
            float4 w1 = ws[(2 * lk2 + 1) * 64 + lane];
            #pragma unroll
            for (int i = 0; i < 4; i++) {
                float a0 = rdlane(xr[i].x, k2);
                float a1 = rdlane(xr[i].y, k2);
                acc[i][0] += a0 * w0.x + a1 * w1.x;
                acc[i][1] += a0 * w0.y + a1 * w1.y;
                acc[i][2] += a0 * w0.z + a1 * w1.z;
                acc[i][3] += a0 * w0.w + a1 * w1.w;
            }
        }
    }
    float4 asv = *(const float4*)(a_src1 + j4);
    float4 adv = *(const float4*)(a_dst1 + j4);
    #pragma unroll
    for (int i = 0; i < 4; i++) {
        int row = base + wv * 4 + i;
        union { bf16 b[4]; ushort4 u; } cv;
        cv.b[0] = __float2bfloat16(acc[i][0]);
        cv.b[1] = __float2bfloat16(acc[i][1]);
        cv.b[2] = __float2bfloat16(acc[i][2]);
        cv.b[3] = __float2bfloat16(acc[i][3]);
        *(ushort4*)(h + (size_t)row * 256 + j4) = cv.u;
        float vs = acc[i][0] * asv.x + acc[i][1] * asv.y + acc[i][2] * asv.z + acc[i][3] * asv.w;
        float vd = acc[i][0] * adv.x + acc[i][1] * adv.y + acc[i][2] * adv.z + acc[i][3] * adv.w;
        #pragma unroll
        for (int o = 1; o < 16; o <<= 1) {
            vs += __shfl_xor(vs, o);
            vd += __shfl_xor(vd, o);
        }
        if ((lane & 15) == 0) {
            as1[row * 4 + (lane >> 4)] = vs;
            ad1[row * 4 + (lane >> 4)] = vd;
        }
    }
}

// ---------------- D2: fused softmax + agg1 + gemm2 (R23: transposed gather) ----------------
// 4096 blocks x 4 nodes; wave = head. R23: phase B LANE = CHANNEL (head width 64 =
// wave width). Per edge: one coalesced 128B wave-load (ushort/lane) + cvt + FMA.
// Kills UNPACK8 shifts, the 3-level cross-lane reduce, and the lane<8 epilogue
// (essential FMA work is ~2us; old structure spent ~32us of VALU). Phase A stores
// (s, t*inv) int2 pairs; phase B reads them via uniform ds_read_b128 broadcast,
// 2-deep software-pipelined so quad q+1's (s,t)+h loads fly during quad q's FMAs.
// LDS 12.3 KB; part (gemm2) aliases sts (dead after phase B barrier).
// NOTE (kernel law, R11/R13): TLP-bound — VGPR must stay < 64.
__global__ __launch_bounds__(256) void k_agg1_gemm2(
        const int* __restrict__ cnt, const int* __restrict__ esrc,
        const float* __restrict__ as1, const float* __restrict__ ad1,
        const bf16* __restrict__ h,
        const float* __restrict__ b1,
        const float* __restrict__ W2,
        const float* __restrict__ a_src2, const float* __restrict__ a_dst2,
        bf16* __restrict__ h2, float* __restrict__ as2, float* __restrict__ ad2) {
    __shared__ float hs[4][256];
    __shared__ int2  sts[16][64];   // (s, t*inv) per (node it, head wv); gemm2 aliases as part
    int tid = threadIdx.x, lane = tid & 63, wv = tid >> 6;
    int dbase = blockIdx.x * 4;

    int cv4 = cnt[dbase + (lane & 3)];               // 4 degrees, one load

    // ---- phase A: normalized per-head edge weights, packed with indices ----
    #pragma unroll
    for (int it = 0; it < 4; it++) {
        int d = dbase + it;
        int deg = min(__shfl(cv4, it), SLOTS);
        int s = esrc[(size_t)d * SLOTS + lane] & (N_NODES - 1);   // tail -> masked idx
        float av = as1[(size_t)s * 4 + wv];
        float adw = ad1[d * 4 + wv];
        float t = (lane < deg) ? __expf(lrelu(av + adw) - 40.f) : 0.f;
        float inv = 1.f / wave_sum(t);                // den > 0 (self-loop)
        int2 pr; pr.x = s; pr.y = __float_as_int(t * inv);
        sts[it * 4 + wv][lane] = pr;
    }
    // no barrier: each wave reads only sts rows it wrote itself

    // ---- phase B: lane = channel; per-edge coalesced 128B gathers, 2-deep pipeline ----
    const unsigned short* hb = (const unsigned short*)h + (size_t)wv * 64 + lane;
    float bb = b1[wv * 64 + lane];
    #pragma unroll 2
    for (int it = 0; it < 4; it++) {
        int deg = min(__shfl(cv4, it), SLOTS);
        const int4* row4 = (const int4*)sts[it * 4 + wv];   // (s0,t0,s1,t1) per int4
        int nq = (deg + 3) >> 2;                            // quads of 4 edges; tails t=0
        float acc = 0.f;
        int4 A = row4[0];
        int4 B = row4[1];
        unsigned short e0 = hb[(size_t)A.x * 256];
        unsigned short e1 = hb[(size_t)A.z * 256];
        unsigned short e2 = hb[(size_t)B.x * 256];
        unsigned short e3 = hb[(size_t)B.z * 256];
        for (int q = 1; q < nq; q++) {
            int4 An = row4[2 * q];
            int4 Bn = row4[2 * q + 1];
            unsigned short f0 = hb[(size_t)An.x * 256];
            unsigned short f1 = hb[(size_t)An.z * 256];
            unsigned short f2 = hb[(size_t)Bn.x * 256];
            unsigned short f3 = hb[(size_t)Bn.z * 256];
            acc += bfu(e0) * __uint_as_float(A.y);
            acc += bfu(e1) * __uint_as_float(A.w);
            acc += bfu(e2) * __uint_as_float(B.y);
            acc += bfu(e3) * __uint_as_float(B.w);
            A = An; B = Bn; e0 = f0; e1 = f1; e2 = f2; e3 = f3;
        }
        acc += bfu(e0) * __uint_as_float(A.y);
        acc += bfu(e1) * __uint_as_float(A.w);
        acc += bfu(e2) * __uint_as_float(B.y);
        acc += bfu(e3) * __uint_as_float(B.w);
        float v = acc + bb;
        hs[it][wv * 64 + lane] = v > 0.f ? v : (__expf(v) - 1.f);   // elu, all 64 lanes
    }
    __syncthreads();   // hs complete; sts dead from here -> reuse as part

    float* part = (float*)sts;   // 4 KB of the 8 KB sts buffer

    // ---- gemm2 on the 4 rows in LDS, K-split across the 4 waves ----
    {
        float acc2[4] = {0, 0, 0, 0};
        const int k4base = wv * 16;
        for (int kk = 0; kk < 16; kk++) {
            int k4 = k4base + kk;
            const float* wp = W2 + (size_t)k4 * 256 + lane;   // W2[(k4*4+q)*64 + lane]
            float w0 = wp[0], w1 = wp[64], w2 = wp[128], w3 = wp[192];
            #pragma unroll
            for (int r = 0; r < 4; r++) {
                float4 u = *(const float4*)&hs[r][k4 * 4];    // wave-uniform -> broadcast
                acc2[r] += u.x * w0 + u.y * w1 + u.z * w2 + u.w * w3;
            }
        }
        #pragma unroll
        for (int r = 0; r < 4; r++) part[(wv * 4 + r) * 64 + lane] = acc2[r];
    }
    __syncthreads();
    {
        int r = wv;                                   // one row per wave
        float a0 = part[(0 * 4 + r) * 64 + lane] + part[(1 * 4 + r) * 64 + lane]
                 + part[(2 * 4 + r) * 64 + lane] + part[(3 * 4 + r) * 64 + lane];
        float asj = a_src2[lane], adj = a_dst2[lane];
        int n0 = dbase + r;
        h2[(size_t)n0 * 64 + lane] = __float2bfloat16(a0);
        float va0 = wave_sum(a0 * asj);
        float vd0 = wave_sum(a0 * adj);
        if (lane == 0) {
            as2[n0] = va0; ad2[n0] = vd0;
        }
    }
}

// ---------------- D3: fused softmax + agg2 -> out (R23: transposed gather) ----------------
// Wave per node; lane = channel (HID 64 = wave width). Direct coalesced out write.
__global__ __launch_bounds__(256) void k_agg2(const int* __restrict__ cnt,
                                              const int* __restrict__ esrc,
                                              const float* __restrict__ as2,
                                              const float* __restrict__ ad2,
                                              const bf16* __restrict__ h2,
                                              const float* __restrict__ b2v,
                                              float* __restrict__ out) {
    __shared__ int2 sts2[4][64];
    int tid = threadIdx.x, lane = tid & 63, wv = tid >> 6;
    int d = blockIdx.x * 4 + wv;
    int deg = min(cnt[d], SLOTS);

    // phase A: per-edge normalized weights (lane = slot)
    int s = esrc[(size_t)d * SLOTS + lane] & (N_NODES - 1);
    float av = as2[s];
    float adw = ad2[d];
    float t = (lane < deg) ? __expf(lrelu(av + adw) - 40.f) : 0.f;
    float inv = 1.f / wave_sum(t);
    int2 pr; pr.x = s; pr.y = __float_as_int(t * inv);
    sts2[wv][lane] = pr;
    // no barrier: wave reads only its own row

    // phase B: lane = channel; 2-deep pipelined edge loop
    const unsigned short* hb = (const unsigned short*)h2 + lane;
    const int4* row4 = (const int4*)sts2[wv];
    int nq = (deg + 3) >> 2;
    float acc = 0.f;
    int4 A = row4[0];
    int4 B = row4[1];
    unsigned short e0 = hb[(size_t)A.x * 64];
    unsigned short e1 = hb[(size_t)A.z * 64];
    unsigned short e2 = hb[(size_t)B.x * 64];
    unsigned short e3 = hb[(size_t)B.z * 64];
    for (int q = 1; q < nq; q++) {
        int4 An = row4[2 * q];
        int4 Bn = row4[2 * q + 1];
        unsigned short f0 = hb[(size_t)An.x * 64];
        unsigned short f1 = hb[(size_t)An.z * 64];
        unsigned short f2 = hb[(size_t)Bn.x * 64];
        unsigned short f3 = hb[(size_t)Bn.z * 64];
        acc += bfu(e0) * __uint_as_float(A.y);
        acc += bfu(e1) * __uint_as_float(A.w);
        acc += bfu(e2) * __uint_as_float(B.y);
        acc += bfu(e3) * __uint_as_float(B.w);
        A = An; B = Bn; e0 = f0; e1 = f1; e2 = f2; e3 = f3;
    }
    acc += bfu(e0) * __uint_as_float(A.y);
    acc += bfu(e1) * __uint_as_float(A.w);
    acc += bfu(e2) * __uint_as_float(B.y);
    acc += bfu(e3) * __uint_as_float(B.w);
    out[(size_t)d * 64 + lane] = acc + b2v[lane];
}

extern "C" void kernel_launch(void* const* d_in, const int* in_sizes, int n_in,
                              void* d_out, int out_size, void* d_ws, size_t ws_size,
                              hipStream_t stream) {
    const float* x    = (const float*)d_in[0];
    const int*   ei   = (const int*)  d_in[1];
    const float* pe   = (const float*)d_in[2];
    const float* W1   = (const float*)d_in[3];
    const float* a_s1 = (const float*)d_in[4];
    const float* a_d1 = (const float*)d_in[5];
    const float* b1   = (const float*)d_in[6];
    const float* W2   = (const float*)d_in[7];
    const float* a_s2 = (const float*)d_in[8];
    const float* a_d2 = (const float*)d_in[9];
    const float* b2   = (const float*)d_in[10];

    const int E    = in_sizes[1] / 2;
    const int n    = N_NODES;
    const int Etot = E + n;

    // workspace carve-up (256B aligned) — footprint ~14.6 MB
    char* p = (char*)d_ws;
    auto alloc = [&](size_t bytes) -> void* {
        void* r = (void*)p;
        p += (bytes + 255) & ~(size_t)255;
        return r;
    };
    int*   cnt     = (int*)  alloc((size_t)n * 4);
    int*   esrc    = (int*)  alloc((size_t)n * SLOTS * 4);
    bf16*  h       = (bf16*) alloc((size_t)n * F1 * 2);
    float* as1     = (float*)alloc((size_t)n * HEADS * 4);
    float* ad1     = (float*)alloc((size_t)n * HEADS * 4);
    bf16*  h2      = (bf16*) alloc((size_t)n * HID * 2);
    float* as2     = (float*)alloc((size_t)n * 4);
    float* ad2     = (float*)alloc((size_t)n * 4);

    hipMemsetAsync(cnt, 0, (size_t)n * 4, stream);   // cnt zeroing

    k_gemm1s    <<<n / 16, 256, 0, stream>>>(x, pe, W1, a_s1, a_d1, h, as1, ad1,
                                             ei, E, Etot, cnt, esrc);
    k_agg1_gemm2<<<n / 4, 256, 0, stream>>>(cnt, esrc, as1, ad1, h, b1,
                                            W2, a_s2, a_d2, h2, as2, ad2);
    k_agg2      <<<n / 4, 256, 0, stream>>>(cnt, esrc, as2, ad2, h2, b2, (float*)d_out);
}